// Round 15
// baseline (202.451 us; speedup 1.0000x reference)
//
#include <hip/hip_runtime.h>

#define S_LEN 2048
#define N_B 2
#define N_H 16
#define N_KVH 4
#define HD 128
#define LDQ 2048   // N_H*HD
#define LDK 512    // dense K buffer leading dim

typedef __bf16 bf16x8 __attribute__((ext_vector_type(8)));
typedef float f32x4 __attribute__((ext_vector_type(4)));
typedef float f32x16 __attribute__((ext_vector_type(16)));
typedef int v2i __attribute__((ext_vector_type(2)));

__device__ __forceinline__ float bf2f(unsigned short u){
  unsigned int x = ((unsigned int)u) << 16; float f;
  __builtin_memcpy(&f, &x, 4); return f;
}
__device__ __forceinline__ unsigned short f2bf(float f){
  unsigned int x; __builtin_memcpy(&x, &f, 4);
  unsigned int r = x + 0x7fff + ((x >> 16) & 1);
  return (unsigned short)(r >> 16);
}
__device__ __forceinline__ unsigned int cvt_pk_bf16(float lo, float hi){
  unsigned int u;
  asm("v_cvt_pk_bf16_f32 %0, %1, %2" : "=v"(u) : "v"(lo), "v"(hi));
  return u;
}
__device__ __forceinline__ void gload16(const void* g, void* l){
  __builtin_amdgcn_global_load_lds((const __attribute__((address_space(1))) void*)g,
                                   (__attribute__((address_space(3))) void*)l, 16, 0, 0);
}

// ---------------- fused cast fp32 -> bf16 for x + all weights ----------------
__global__ void cast_all(const float* __restrict__ x,  const float* __restrict__ wq,
                         const float* __restrict__ wk, const float* __restrict__ wv,
                         const float* __restrict__ wo, unsigned short* __restrict__ xb,
                         unsigned short* __restrict__ wqb, unsigned short* __restrict__ wkb,
                         unsigned short* __restrict__ wvb, unsigned short* __restrict__ wob){
  int i = blockIdx.x * 256 + threadIdx.x;   // grid covers 2359296 groups of 8
  const float* in; unsigned short* out; int j;
  if (i < 1048576)      { in = x;  out = xb;  j = i; }
  else if (i < 1572864) { in = wq; out = wqb; j = i - 1048576; }
  else if (i < 1703936) { in = wk; out = wkb; j = i - 1572864; }
  else if (i < 1835008) { in = wv; out = wvb; j = i - 1703936; }
  else                  { in = wo; out = wob; j = i - 1835008; }
  const float4* p = (const float4*)in + (size_t)j * 2;
  float4 a = p[0], b = p[1];
  uint4 o;
  o.x = (unsigned)f2bf(a.x) | ((unsigned)f2bf(a.y) << 16);
  o.y = (unsigned)f2bf(a.z) | ((unsigned)f2bf(a.w) << 16);
  o.z = (unsigned)f2bf(b.x) | ((unsigned)f2bf(b.y) << 16);
  o.w = (unsigned)f2bf(b.z) | ((unsigned)f2bf(b.w) << 16);
  ((uint4*)out)[j] = o;
}

// ---------------- RoPE for K only (dense [4096,512]), in-place ----------------
__global__ void rope_k(unsigned short* __restrict__ Kbuf, const float* __restrict__ FC){
  int i = blockIdx.x * 256 + threadIdx.x;   // 262144 groups of 8 -> 1024 blocks
  int row = i >> 6, col = (i & 63) << 3;
  unsigned short* X = Kbuf + (((size_t)row) << 9) + col;
  int s = row & (S_LEN - 1);
  int d = col & (HD - 1);
  uint4 v = *(const uint4*)X;
  unsigned short* pv = (unsigned short*)&v;
  const float4* f4 = (const float4*)FC + ((size_t)s * 64 + (d >> 1));
  uint4 ov; unsigned short* po = (unsigned short*)&ov;
#pragma unroll
  for (int p = 0; p < 4; p++){
    float4 f = f4[p];
    float e = bf2f(pv[2*p]), o = bf2f(pv[2*p+1]);
    po[2*p]   = f2bf(f.x * e + f.y * o);
    po[2*p+1] = f2bf(f.z * e + f.w * o);
  }
  *(uint4*)X = ov;
}

__device__ __forceinline__ void storeC(float* C, size_t idx, float v){ C[idx] = v; }
__device__ __forceinline__ void storeC(unsigned short* C, size_t idx, float v){ C[idx] = f2bf(v); }

// ---------------- fused QKV projection: 128x256 tile, 8 waves, triple-buffer, counted vmcnt.
// B = [wq|wk|wv] (3072 x 2048). Epilogue routes: cols<2048 -> Qo (ld 2048, UNROPED),
// 2048..2559 -> Ko (ld 512), >=2560 -> Vt TRANSPOSED ([b,kvh,d][s], uint2 packed).
__global__ __launch_bounds__(512, 2) void gemm_qkv(const unsigned short* __restrict__ A,
                                                   const unsigned short* __restrict__ Bm,
                                                   unsigned short* __restrict__ Qo,
                                                   unsigned short* __restrict__ Ko,
                                                   unsigned short* __restrict__ Vt){
  extern __shared__ char smem[];   // 3 slots x (sA 16KB | sB 32KB) = 144KB
  const int K = 2048;
  int bid = blockIdx.x;
  bid = (bid & 7) * 48 + (bid >> 3);   // XCD swizzle (384 % 8 == 0)
  int bn = bid % 12, bm = bid / 12;
  int row0 = bm * 128, col0 = bn * 256;
  int t = threadIdx.x, w = t >> 6, l = t & 63;
  int lr = l & 15, lg = l >> 4;
  int wm = w >> 2, wn = w & 3;         // 2 x 4 wave grid, per-wave 64x64 output
  int srow = t >> 3;
  int sg = (t & 7) ^ (srow & 7);
  const unsigned short* agp = A + (size_t)(row0 + srow) * K + sg * 8;
  const unsigned short* bgp = Bm + (size_t)(col0 + srow) * K + sg * 8;
  int nk = K >> 6;
  f32x4 acc[4][4] = {};

#define TPL_STAGE(j, s) do {                                                   \
    char* base_ = smem + (s) * 49152;                                          \
    int k0_ = (j) << 6;                                                        \
    _Pragma("unroll")                                                          \
    for (int i_ = 0; i_ < 2; i_++)                                             \
      gload16(agp + (size_t)i_ * 64 * K + k0_, base_ + i_ * 8192 + w * 1024);  \
    _Pragma("unroll")                                                          \
    for (int i_ = 0; i_ < 4; i_++)                                             \
      gload16(bgp + (size_t)i_ * 64 * K + k0_, base_ + 16384 + i_ * 8192 + w * 1024); \
  } while(0)

  TPL_STAGE(0, 0);
  TPL_STAGE(1, 1);
  int slot = 0;
  for (int j = 0; j < nk; j++){
    if (j + 1 < nk) asm volatile("s_waitcnt vmcnt(6)" ::: "memory");
    else            asm volatile("s_waitcnt vmcnt(0)" ::: "memory");
    __builtin_amdgcn_s_barrier();
    asm volatile("" ::: "memory");
    char* sA = smem + slot * 49152;
    char* sB = sA + 16384;
    bf16x8 af[2][4], bf[2][4];
#pragma unroll
    for (int kk = 0; kk < 2; kk++){
#pragma unroll
      for (int m = 0; m < 4; m++){
        int row = wm * 64 + m * 16 + lr;
        int kg = kk * 4 + lg;
        af[kk][m] = *(const bf16x8*)(sA + row * 128 + ((kg ^ (row & 7)) << 4));
      }
#pragma unroll
      for (int n = 0; n < 4; n++){
        int row = wn * 64 + n * 16 + lr;
        int kg = kk * 4 + lg;
        bf[kk][n] = *(const bf16x8*)(sB + row * 128 + ((kg ^ (row & 7)) << 4));
      }
    }
    if (j + 2 < nk){
      int sn = slot + 2; if (sn >= 3) sn -= 3;
      TPL_STAGE(j + 2, sn);
    }
    __builtin_amdgcn_s_setprio(1);
#pragma unroll
    for (int kk = 0; kk < 2; kk++)
#pragma unroll
      for (int m = 0; m < 4; m++)
#pragma unroll
        for (int n = 0; n < 4; n++)
          acc[m][n] = __builtin_amdgcn_mfma_f32_16x16x32_bf16(af[kk][m], bf[kk][n], acc[m][n], 0, 0, 0);
    __builtin_amdgcn_s_setprio(0);
    slot++; if (slot == 3) slot = 0;
  }
#undef TPL_STAGE
  // ---- epilogue: route by block-uniform column range ----
  if (col0 < 2048){
#pragma unroll
    for (int m = 0; m < 4; m++)
#pragma unroll
      for (int n = 0; n < 4; n++)
#pragma unroll
        for (int r = 0; r < 4; r++){
          int rr = row0 + wm * 64 + m * 16 + lg * 4 + r;
          int cc = col0 + wn * 64 + n * 16 + lr;
          Qo[(size_t)rr * 2048 + cc] = f2bf(acc[m][n][r]);
        }
  } else if (col0 < 2560){
#pragma unroll
    for (int m = 0; m < 4; m++)
#pragma unroll
      for (int n = 0; n < 4; n++)
#pragma unroll
        for (int r = 0; r < 4; r++){
          int rr = row0 + wm * 64 + m * 16 + lg * 4 + r;
          int cc = col0 - 2048 + wn * 64 + n * 16 + lr;
          Ko[(size_t)rr * 512 + cc] = f2bf(acc[m][n][r]);
        }
  } else {
#pragma unroll
    for (int m = 0; m < 4; m++)
#pragma unroll
      for (int n = 0; n < 4; n++){
        int vcol = col0 - 2560 + wn * 64 + n * 16 + lr;   // 0..511
        int kvh = vcol >> 7, d = vcol & (HD - 1);
        int s0 = row0 + wm * 64 + m * 16 + lg * 4;        // 4 consecutive tokens
        int bb = s0 >> 11, sl = s0 & (S_LEN - 1);
        uint2 o2;
        o2.x = cvt_pk_bf16(acc[m][n][0], acc[m][n][1]);
        o2.y = cvt_pk_bf16(acc[m][n][2], acc[m][n][3]);
        *(uint2*)(Vt + ((size_t)((bb * N_KVH + kvh) * HD + d)) * S_LEN + sl) = o2;
      }
  }
}

// ---------------- pipelined NT GEMM (wo projection): 128x256 tile, triple-buffer ----------------
template <typename OutT>
__global__ __launch_bounds__(512, 2) void gemm_tpl(const unsigned short* __restrict__ A,
                                                   const unsigned short* __restrict__ Bm,
                                                   OutT* __restrict__ C,
                                                   int M, int N, int K, int nbn){
  extern __shared__ char smem[];   // 3 slots x (sA 16KB | sB 32KB) = 144KB
  int bid = blockIdx.x;
  bid = (bid & 7) * (gridDim.x >> 3) + (bid >> 3);   // XCD swizzle (nwg % 8 == 0)
  int bn = bid % nbn, bm = bid / nbn;
  int row0 = bm * 128, col0 = bn * 256;
  int t = threadIdx.x, w = t >> 6, l = t & 63;
  int lr = l & 15, lg = l >> 4;
  int wm = w >> 2, wn = w & 3;
  int srow = t >> 3;
  int sg = (t & 7) ^ (srow & 7);
  const unsigned short* agp = A + (size_t)(row0 + srow) * K + sg * 8;
  const unsigned short* bgp = Bm + (size_t)(col0 + srow) * K + sg * 8;
  int nk = K >> 6;
  f32x4 acc[4][4] = {};

#define TPL_STAGE(j, s) do {                                                   \
    char* base_ = smem + (s) * 49152;                                          \
    int k0_ = (j) << 6;                                                        \
    _Pragma("unroll")                                                          \
    for (int i_ = 0; i_ < 2; i_++)                                             \
      gload16(agp + (size_t)i_ * 64 * K + k0_, base_ + i_ * 8192 + w * 1024);  \
    _Pragma("unroll")                                                          \
    for (int i_ = 0; i_ < 4; i_++)                                             \
      gload16(bgp + (size_t)i_ * 64 * K + k0_, base_ + 16384 + i_ * 8192 + w * 1024); \
  } while(0)

  TPL_STAGE(0, 0);
  TPL_STAGE(1, 1);
  int slot = 0;
  for (int j = 0; j < nk; j++){
    if (j + 1 < nk) asm volatile("s_waitcnt vmcnt(6)" ::: "memory");
    else            asm volatile("s_waitcnt vmcnt(0)" ::: "memory");
    __builtin_amdgcn_s_barrier();
    asm volatile("" ::: "memory");
    char* sA = smem + slot * 49152;
    char* sB = sA + 16384;
    bf16x8 af[2][4], bf[2][4];
#pragma unroll
    for (int kk = 0; kk < 2; kk++){
#pragma unroll
      for (int m = 0; m < 4; m++){
        int row = wm * 64 + m * 16 + lr;
        int kg = kk * 4 + lg;
        af[kk][m] = *(const bf16x8*)(sA + row * 128 + ((kg ^ (row & 7)) << 4));
      }
#pragma unroll
      for (int n = 0; n < 4; n++){
        int row = wn * 64 + n * 16 + lr;
        int kg = kk * 4 + lg;
        bf[kk][n] = *(const bf16x8*)(sB + row * 128 + ((kg ^ (row & 7)) << 4));
      }
    }
    if (j + 2 < nk){
      int sn = slot + 2; if (sn >= 3) sn -= 3;
      TPL_STAGE(j + 2, sn);
    }
    __builtin_amdgcn_s_setprio(1);
#pragma unroll
    for (int kk = 0; kk < 2; kk++)
#pragma unroll
      for (int m = 0; m < 4; m++)
#pragma unroll
        for (int n = 0; n < 4; n++)
          acc[m][n] = __builtin_amdgcn_mfma_f32_16x16x32_bf16(af[kk][m], bf[kk][n], acc[m][n], 0, 0, 0);
    __builtin_amdgcn_s_setprio(0);
    slot++; if (slot == 3) slot = 0;
  }
#undef TPL_STAGE
#pragma unroll
  for (int m = 0; m < 4; m++)
#pragma unroll
    for (int n = 0; n < 4; n++)
#pragma unroll
      for (int r = 0; r < 4; r++){
        int rr = row0 + wm * 64 + m * 16 + lg * 4 + r;
        int cc = col0 + wn * 64 + n * 16 + lr;
        storeC(C, (size_t)rr * N + cc, acc[m][n][r]);
      }
}

// ---------------- flash attention fwd (R7/R11 config) + fused Q-RoPE at load ----------------
// grid 512 = b(2) x h(16) x slot(16); slot = {pair p in 0..7, half}. QBLK=128 (4 waves x 32q).
// Per q-tile qt: kv-tiles(64) lo [0,qt+1), hi [qt+1,2qt+2) -> exactly 17 tiles per block.
// Q is UNROPED in global; rope applied in-register (pairs are in-lane within each bf16x8).
__global__ __launch_bounds__(256, 2) void attn_fwd(const unsigned short* __restrict__ Q,
                                                   const unsigned short* __restrict__ Kb,
                                                   const unsigned short* __restrict__ Vt,
                                                   const float* __restrict__ FC,
                                                   unsigned short* __restrict__ P0,
                                                   unsigned short* __restrict__ P1,
                                                   float2* __restrict__ ML){
  extern __shared__ char smem[];  // 2 x (sK 16KB | sV 16KB) = 64KB
  const float SOFT_C = 0.088388347648318447f * 1.4426950408889634f; // scale*log2(e)
  const float THR_RAW = 62.0f;                                      // ~8 / SOFT_C
  int bid = blockIdx.x;
  bid = ((bid & 7) << 6) | (bid >> 3);   // XCD swizzle: 64 consecutive logical per XCD
  int slot = bid & 15, h = (bid >> 4) & 15, b = bid >> 8;
  int p = slot & 7, half = slot >> 3;
  int kvh = h >> 2;
  int t = threadIdx.x, w = t >> 6, l = t & 63;
  int lq = l & 31, lh = l >> 5;
  unsigned short* Pout = half ? P1 : P0;
  float2* mlb = ML + half * (N_B * S_LEN * N_H);

  // ---- staging pointers (source pre-swizzled; LDS dest linear) ----
  int gA = (t & 15) ^ (t >> 4);
  const unsigned short* kgp = Kb + ((size_t)(b * S_LEN) + (t >> 4)) * LDK + kvh * HD + gA * 8;
  int gV = (t & 7) ^ ((t >> 3) & 7);
  const unsigned short* vgp = Vt + ((size_t)((b * N_KVH + kvh) * HD) + (t >> 3)) * S_LEN + gV * 8;

  for (int phase = 0; phase < 2; phase++){
    int qt = phase ? (15 - p) : p;
    int q_lane = qt * 128 + w * 32 + lq;
    const unsigned short* qbase = Q + ((size_t)(b * S_LEN + q_lane)) * LDQ + h * HD + lh * 8;
    const float4* fb = (const float4*)FC + (size_t)q_lane * 64 + lh * 4;
    bf16x8 qf[8];
#pragma unroll
    for (int ks = 0; ks < 8; ks++){
      bf16x8 raw = *(const bf16x8*)(qbase + ks * 16);
      unsigned short pr[8];
      __builtin_memcpy(pr, &raw, 16);
      unsigned int u[4];
#pragma unroll
      for (int j = 0; j < 4; j++){
        float4 f = fb[ks * 8 + j];
        float e = bf2f(pr[2*j]), o = bf2f(pr[2*j+1]);
        u[j] = cvt_pk_bf16(f.x * e + f.y * o, f.z * e + f.w * o);
      }
      __builtin_memcpy(&qf[ks], u, 16);
    }

    f32x16 o_acc[4] = {};
    float m_run = -1e4f, l_run = 0.f;
    int t_begin = half ? (qt + 1) : 0;
    int t_end   = half ? (2 * qt + 2) : (qt + 1);

    // prologue: stage tile t_begin into buffer 0
    int pk0 = t_begin * 64;
#pragma unroll
    for (int m = 0; m < 4; m++)
      gload16(kgp + (size_t)(pk0 + m * 16) * LDK, smem + m * 4096 + w * 1024);
#pragma unroll
    for (int i = 0; i < 4; i++)
      gload16(vgp + (size_t)i * 32 * S_LEN + pk0, smem + 16384 + i * 4096 + w * 1024);
    __syncthreads();

    int cur = 0;
    for (int tix = t_begin; tix < t_end; tix++){
      int k0 = tix * 64;
      char* sK = smem + (cur << 15);
      char* sV = sK + 16384;
      if (tix + 1 < t_end){
        char* nb = smem + ((cur ^ 1) << 15);
        int nk0 = k0 + 64;
#pragma unroll
        for (int m = 0; m < 4; m++)
          gload16(kgp + (size_t)(nk0 + m * 16) * LDK, nb + m * 4096 + w * 1024);
#pragma unroll
        for (int i = 0; i < 4; i++)
          gload16(vgp + (size_t)i * 32 * S_LEN + nk0, nb + 16384 + i * 4096 + w * 1024);
      }

      // ---- QK^T (swapped): sc[n] = S^T, row=kv = n*32+(reg&3)+8*(reg>>2)+4*lh, col=q=lq ----
      f32x16 sc[2] = {};
      __builtin_amdgcn_s_setprio(1);
#pragma unroll
      for (int ks = 0; ks < 8; ks++){
#pragma unroll
        for (int n = 0; n < 2; n++){
          int row = n * 32 + lq;
          int pg = (ks * 2 + lh) ^ (row & 15);
          bf16x8 kf = *(const bf16x8*)(sK + row * 256 + pg * 16);
          sc[n] = __builtin_amdgcn_mfma_f32_32x32x16_bf16(kf, qf[ks], sc[n], 0, 0, 0);
        }
      }
      __builtin_amdgcn_s_setprio(0);
      // ---- causal mask: only the last two global tiles of this q-tile intersect the diagonal ----
      if (tix >= 2 * qt){
#pragma unroll
        for (int n = 0; n < 2; n++)
#pragma unroll
          for (int reg = 0; reg < 16; reg++){
            int kv = k0 + n * 32 + (reg & 3) + 8 * (reg >> 2) + 4 * lh;
            if (kv > q_lane) sc[n][reg] = -1e30f;
          }
      }
      // ---- online softmax (defer-max); lanes l, l^32 share q-row ----
      float tmax = sc[0][0];
#pragma unroll
      for (int n = 0; n < 2; n++)
#pragma unroll
        for (int reg = 0; reg < 16; reg++) tmax = fmaxf(tmax, sc[n][reg]);
      tmax = fmaxf(tmax, __shfl_xor(tmax, 32));
      if (!__all(tmax - m_run <= THR_RAW)){
        float nm = fmaxf(m_run, tmax);
        float rs = exp2f((m_run - nm) * SOFT_C);
        m_run = nm;
        l_run *= rs;
#pragma unroll
        for (int n = 0; n < 4; n++)
#pragma unroll
          for (int j = 0; j < 16; j++) o_acc[n][j] *= rs;
      }
      float lsum = 0.f;
#pragma unroll
      for (int n = 0; n < 2; n++)
#pragma unroll
        for (int reg = 0; reg < 16; reg++){
          float pv = exp2f((sc[n][reg] - m_run) * SOFT_C);
          sc[n][reg] = pv;
          lsum += pv;
        }
      lsum += __shfl_xor(lsum, 32);
      l_run += lsum;

      // ---- P^T -> PV B-frags: 4 cvt_pk + 2 permlane32_swap per k-step ----
      bf16x8 pb[4];
#pragma unroll
      for (int ks = 0; ks < 4; ks++){
        int n = ks >> 1;
        int R0 = (2 * ks) & 3, R1 = (2 * ks + 1) & 3;
        unsigned int WA0 = cvt_pk_bf16(sc[n][4 * R0 + 0], sc[n][4 * R0 + 1]);
        unsigned int WA1 = cvt_pk_bf16(sc[n][4 * R0 + 2], sc[n][4 * R0 + 3]);
        unsigned int WB0 = cvt_pk_bf16(sc[n][4 * R1 + 0], sc[n][4 * R1 + 1]);
        unsigned int WB1 = cvt_pk_bf16(sc[n][4 * R1 + 2], sc[n][4 * R1 + 3]);
        v2i s0 = __builtin_amdgcn_permlane32_swap((int)WA0, (int)WB0, false, false);
        v2i s1 = __builtin_amdgcn_permlane32_swap((int)WA1, (int)WB1, false, false);
        unsigned int pu[4] = {(unsigned int)s0.x, (unsigned int)s1.x,
                              (unsigned int)s0.y, (unsigned int)s1.y};
        pb[ks] = *(bf16x8*)pu;
      }
      // ---- PV: O^T += V^T * P^T ----
      __builtin_amdgcn_s_setprio(1);
#pragma unroll
      for (int n = 0; n < 4; n++){
#pragma unroll
        for (int ks = 0; ks < 4; ks++){
          int row = n * 32 + lq;
          int pg = (ks * 2 + lh) ^ (row & 7);
          bf16x8 vf = *(const bf16x8*)(sV + row * 128 + pg * 16);
          o_acc[n] = __builtin_amdgcn_mfma_f32_32x32x16_bf16(vf, pb[ks], o_acc[n], 0, 0, 0);
        }
      }
      __builtin_amdgcn_s_setprio(0);
      __syncthreads();
      cur ^= 1;
    }
    // ---- epilogue: UNNORMALIZED partial; lane holds O^T col q=lq, rows d = n*32+8g+4lh+(0..3) ----
    unsigned short* ob = Pout + ((size_t)(b * S_LEN + q_lane)) * LDQ + h * HD + 4 * lh;
#pragma unroll
    for (int n = 0; n < 4; n++)
#pragma unroll
      for (int g = 0; g < 4; g++){
        unsigned int u0 = cvt_pk_bf16(o_acc[n][4 * g + 0], o_acc[n][4 * g + 1]);
        unsigned int u1 = cvt_pk_bf16(o_acc[n][4 * g + 2], o_acc[n][4 * g + 3]);
        uint2 o2; o2.x = u0; o2.y = u1;
        *(uint2*)(ob + n * 32 + g * 8) = o2;
      }
    if (lh == 0)
      mlb[(size_t)(b * S_LEN + q_lane) * N_H + h] = make_float2(m_run, l_run);
  }
}

// ---------------- merge the two kv-half partials ----------------
__global__ void attn_merge(unsigned short* __restrict__ P0, const unsigned short* __restrict__ P1,
                           const float2* __restrict__ ML){
  const float SOFT_C = 0.088388347648318447f * 1.4426950408889634f;
  int tid = blockIdx.x * 256 + threadIdx.x;
  float2 a = ML[tid >> 4];
  float2 c = ML[(N_B * S_LEN * N_H) + (tid >> 4)];
  float m = fmaxf(a.x, c.x);
  float w0 = exp2f((a.x - m) * SOFT_C) * a.y;
  float w1 = exp2f((c.x - m) * SOFT_C) * c.y;
  float inv = 1.0f / (w0 + w1);
  float s0 = exp2f((a.x - m) * SOFT_C) * inv;
  float s1 = exp2f((c.x - m) * SOFT_C) * inv;
  uint4 u0 = *(const uint4*)(P0 + (size_t)tid * 8);
  uint4 u1 = *(const uint4*)(P1 + (size_t)tid * 8);
  unsigned short* q0 = (unsigned short*)&u0;
  unsigned short* q1 = (unsigned short*)&u1;
  uint4 o;
  unsigned int* po = (unsigned int*)&o;
#pragma unroll
  for (int j = 0; j < 4; j++){
    float lo = s0 * bf2f(q0[2*j])   + s1 * bf2f(q1[2*j]);
    float hi = s0 * bf2f(q0[2*j+1]) + s1 * bf2f(q1[2*j+1]);
    po[j] = cvt_pk_bf16(lo, hi);
  }
  *(uint4*)(P0 + (size_t)tid * 8) = o;
}

extern "C" void kernel_launch(void* const* d_in, const int* in_sizes, int n_in,
                              void* d_out, int out_size, void* d_ws, size_t ws_size,
                              hipStream_t stream) {
  const float* x  = (const float*)d_in[0];
  const float* fc = (const float*)d_in[1];
  const float* wq = (const float*)d_in[2];
  const float* wk = (const float*)d_in[3];
  const float* wv = (const float*)d_in[4];
  const float* wo = (const float*)d_in[5];
  float* out = (float*)d_out;

  char* ws = (char*)d_ws;
  unsigned short* xb  = (unsigned short*)(ws);                 // 16 MB; reused as P1 during attn
  unsigned short* wqb = (unsigned short*)(ws + 16777216);      // 8 MB; [wq|wk|wv] contiguous 12 MB
  unsigned short* wkb = (unsigned short*)(ws + 25165824);      // 2 MB
  unsigned short* wvb = (unsigned short*)(ws + 27262976);      // 2 MB
  unsigned short* wob = (unsigned short*)(ws + 29360128);      // 8 MB
  unsigned short* qb_ = (unsigned short*)(ws + 37748736);      // 16 MB  [4096,2048] (unroped)
  unsigned short* kb_ = (unsigned short*)(ws + 54525952);      // 4 MB   [4096,512] roped K
  unsigned short* vtb = (unsigned short*)(ws + 62914560);      // 4 MB   [1024,2048] V^T (from gemm_qkv)
  unsigned short* ab_ = (unsigned short*)(ws + 67108864);      // 16 MB  attn partial lo / merged out
  unsigned short* p1_ = xb;                                    // 16 MB  attn partial hi
  float2*         ml_ = (float2*)wqb;                          // 1 MB   [2][4096*16] (m,l)

  // fused bf16 casts (x + 4 weights), one launch
  cast_all<<<9216, 256, 0, stream>>>(x, wq, wk, wv, wo, xb, wqb, wkb, wvb, wob);

  // fused QKV projection (B = [wq|wk|wv], N=3072): q->qb_, k->kb_, v->vtb transposed
  gemm_qkv<<<384, 512, 147456, stream>>>(xb, wqb, qb_, kb_, vtb);

  // RoPE: K only (Q roped in-register inside attn_fwd)
  rope_k<<<1024, 256, 0, stream>>>(kb_, fc);

  // attention: balanced kv-split, 512 blocks (2/CU), unnormalized partials, fused Q-rope
  attn_fwd<<<512, 256, 65536, stream>>>(qb_, kb_, vtb, fc, ab_, p1_, ml_);
  attn_merge<<<4096, 256, 0, stream>>>(ab_, p1_, ml_);

  // output projection -> fp32 d_out via pipelined template
  gemm_tpl<float><<<256, 512, 147456, stream>>>(ab_, wob, out, 4096, 2048, 2048, 8);
}

// Round 16
// 194.259 us; speedup vs baseline: 1.0422x; 1.0422x over previous
//
#include <hip/hip_runtime.h>

#define S_LEN 2048
#define N_B 2
#define N_H 16
#define N_KVH 4
#define HD 128
#define LDQ 2048   // N_H*HD
#define LDK 512    // dense K buffer leading dim

typedef __bf16 bf16x8 __attribute__((ext_vector_type(8)));
typedef float f32x4 __attribute__((ext_vector_type(4)));
typedef float f32x16 __attribute__((ext_vector_type(16)));
typedef int v2i __attribute__((ext_vector_type(2)));

__device__ __forceinline__ float bf2f(unsigned short u){
  unsigned int x = ((unsigned int)u) << 16; float f;
  __builtin_memcpy(&f, &x, 4); return f;
}
__device__ __forceinline__ unsigned short f2bf(float f){
  unsigned int x; __builtin_memcpy(&x, &f, 4);
  unsigned int r = x + 0x7fff + ((x >> 16) & 1);
  return (unsigned short)(r >> 16);
}
__device__ __forceinline__ unsigned int cvt_pk_bf16(float lo, float hi){
  unsigned int u;
  asm("v_cvt_pk_bf16_f32 %0, %1, %2" : "=v"(u) : "v"(lo), "v"(hi));
  return u;
}
__device__ __forceinline__ void gload16(const void* g, void* l){
  __builtin_amdgcn_global_load_lds((const __attribute__((address_space(1))) void*)g,
                                   (__attribute__((address_space(3))) void*)l, 16, 0, 0);
}

// ---------------- fused cast fp32 -> bf16 for x + all weights ----------------
__global__ void cast_all(const float* __restrict__ x,  const float* __restrict__ wq,
                         const float* __restrict__ wk, const float* __restrict__ wv,
                         const float* __restrict__ wo, unsigned short* __restrict__ xb,
                         unsigned short* __restrict__ wqb, unsigned short* __restrict__ wkb,
                         unsigned short* __restrict__ wvb, unsigned short* __restrict__ wob){
  int i = blockIdx.x * 256 + threadIdx.x;   // grid covers 2359296 groups of 8
  const float* in; unsigned short* out; int j;
  if (i < 1048576)      { in = x;  out = xb;  j = i; }
  else if (i < 1572864) { in = wq; out = wqb; j = i - 1048576; }
  else if (i < 1703936) { in = wk; out = wkb; j = i - 1572864; }
  else if (i < 1835008) { in = wv; out = wvb; j = i - 1703936; }
  else                  { in = wo; out = wob; j = i - 1835008; }
  const float4* p = (const float4*)in + (size_t)j * 2;
  float4 a = p[0], b = p[1];
  uint4 o;
  o.x = (unsigned)f2bf(a.x) | ((unsigned)f2bf(a.y) << 16);
  o.y = (unsigned)f2bf(a.z) | ((unsigned)f2bf(a.w) << 16);
  o.z = (unsigned)f2bf(b.x) | ((unsigned)f2bf(b.y) << 16);
  o.w = (unsigned)f2bf(b.z) | ((unsigned)f2bf(b.w) << 16);
  ((uint4*)out)[j] = o;
}

// ---------------- fused RoPE (q + k) in-place, one launch ----------------
__global__ void rope_both(unsigned short* __restrict__ Qb, unsigned short* __restrict__ Kbuf,
                          const float* __restrict__ FC){
  int i = blockIdx.x * 256 + threadIdx.x;   // 1048576 (q) + 262144 (k) groups -> 5120 blocks
  unsigned short* X; int row, col;
  if (i < 1048576){ row = i >> 8; col = (i & 255) << 3; X = Qb + (((size_t)row) << 11) + col; }
  else { int j = i - 1048576; row = j >> 6; col = (j & 63) << 3; X = Kbuf + (((size_t)row) << 9) + col; }
  int s = row & (S_LEN - 1);
  int d = col & (HD - 1);
  uint4 v = *(const uint4*)X;
  unsigned short* pv = (unsigned short*)&v;
  const float4* f4 = (const float4*)FC + ((size_t)s * 64 + (d >> 1));
  uint4 ov; unsigned short* po = (unsigned short*)&ov;
#pragma unroll
  for (int p = 0; p < 4; p++){
    float4 f = f4[p];
    float e = bf2f(pv[2*p]), o = bf2f(pv[2*p+1]);
    po[2*p]   = f2bf(f.x * e + f.y * o);
    po[2*p+1] = f2bf(f.z * e + f.w * o);
  }
  *(uint4*)X = ov;
}

__device__ __forceinline__ void storeC(float* C, size_t idx, float v){ C[idx] = v; }
__device__ __forceinline__ void storeC(unsigned short* C, size_t idx, float v){ C[idx] = f2bf(v); }

// ---------------- fused QKV projection: 128x256 tile, 8 waves, triple-buffer, counted vmcnt.
// B = [wq|wk|wv] (3072 x 2048). Epilogue routes: cols<2048 -> Qo (ld 2048),
// 2048..2559 -> Ko (ld 512), >=2560 -> Vt TRANSPOSED ([b,kvh,d][s], uint2 packed).
__global__ __launch_bounds__(512, 2) void gemm_qkv(const unsigned short* __restrict__ A,
                                                   const unsigned short* __restrict__ Bm,
                                                   unsigned short* __restrict__ Qo,
                                                   unsigned short* __restrict__ Ko,
                                                   unsigned short* __restrict__ Vt){
  extern __shared__ char smem[];   // 3 slots x (sA 16KB | sB 32KB) = 144KB
  const int K = 2048;
  int bid = blockIdx.x;
  bid = (bid & 7) * 48 + (bid >> 3);   // XCD swizzle (384 % 8 == 0)
  int bn = bid % 12, bm = bid / 12;
  int row0 = bm * 128, col0 = bn * 256;
  int t = threadIdx.x, w = t >> 6, l = t & 63;
  int lr = l & 15, lg = l >> 4;
  int wm = w >> 2, wn = w & 3;         // 2 x 4 wave grid, per-wave 64x64 output
  int srow = t >> 3;
  int sg = (t & 7) ^ (srow & 7);
  const unsigned short* agp = A + (size_t)(row0 + srow) * K + sg * 8;
  const unsigned short* bgp = Bm + (size_t)(col0 + srow) * K + sg * 8;
  int nk = K >> 6;
  f32x4 acc[4][4] = {};

#define TPL_STAGE(j, s) do {                                                   \
    char* base_ = smem + (s) * 49152;                                          \
    int k0_ = (j) << 6;                                                        \
    _Pragma("unroll")                                                          \
    for (int i_ = 0; i_ < 2; i_++)                                             \
      gload16(agp + (size_t)i_ * 64 * K + k0_, base_ + i_ * 8192 + w * 1024);  \
    _Pragma("unroll")                                                          \
    for (int i_ = 0; i_ < 4; i_++)                                             \
      gload16(bgp + (size_t)i_ * 64 * K + k0_, base_ + 16384 + i_ * 8192 + w * 1024); \
  } while(0)

  TPL_STAGE(0, 0);
  TPL_STAGE(1, 1);
  int slot = 0;
  for (int j = 0; j < nk; j++){
    if (j + 1 < nk) asm volatile("s_waitcnt vmcnt(6)" ::: "memory");
    else            asm volatile("s_waitcnt vmcnt(0)" ::: "memory");
    __builtin_amdgcn_s_barrier();
    asm volatile("" ::: "memory");
    char* sA = smem + slot * 49152;
    char* sB = sA + 16384;
    bf16x8 af[2][4], bf[2][4];
#pragma unroll
    for (int kk = 0; kk < 2; kk++){
#pragma unroll
      for (int m = 0; m < 4; m++){
        int row = wm * 64 + m * 16 + lr;
        int kg = kk * 4 + lg;
        af[kk][m] = *(const bf16x8*)(sA + row * 128 + ((kg ^ (row & 7)) << 4));
      }
#pragma unroll
      for (int n = 0; n < 4; n++){
        int row = wn * 64 + n * 16 + lr;
        int kg = kk * 4 + lg;
        bf[kk][n] = *(const bf16x8*)(sB + row * 128 + ((kg ^ (row & 7)) << 4));
      }
    }
    if (j + 2 < nk){
      int sn = slot + 2; if (sn >= 3) sn -= 3;
      TPL_STAGE(j + 2, sn);
    }
    __builtin_amdgcn_s_setprio(1);
#pragma unroll
    for (int kk = 0; kk < 2; kk++)
#pragma unroll
      for (int m = 0; m < 4; m++)
#pragma unroll
        for (int n = 0; n < 4; n++)
          acc[m][n] = __builtin_amdgcn_mfma_f32_16x16x32_bf16(af[kk][m], bf[kk][n], acc[m][n], 0, 0, 0);
    __builtin_amdgcn_s_setprio(0);
    slot++; if (slot == 3) slot = 0;
  }
#undef TPL_STAGE
  // ---- epilogue: route by block-uniform column range ----
  if (col0 < 2048){
#pragma unroll
    for (int m = 0; m < 4; m++)
#pragma unroll
      for (int n = 0; n < 4; n++)
#pragma unroll
        for (int r = 0; r < 4; r++){
          int rr = row0 + wm * 64 + m * 16 + lg * 4 + r;
          int cc = col0 + wn * 64 + n * 16 + lr;
          Qo[(size_t)rr * 2048 + cc] = f2bf(acc[m][n][r]);
        }
  } else if (col0 < 2560){
#pragma unroll
    for (int m = 0; m < 4; m++)
#pragma unroll
      for (int n = 0; n < 4; n++)
#pragma unroll
        for (int r = 0; r < 4; r++){
          int rr = row0 + wm * 64 + m * 16 + lg * 4 + r;
          int cc = col0 - 2048 + wn * 64 + n * 16 + lr;
          Ko[(size_t)rr * 512 + cc] = f2bf(acc[m][n][r]);
        }
  } else {
#pragma unroll
    for (int m = 0; m < 4; m++)
#pragma unroll
      for (int n = 0; n < 4; n++){
        int vcol = col0 - 2560 + wn * 64 + n * 16 + lr;   // 0..511
        int kvh = vcol >> 7, d = vcol & (HD - 1);
        int s0 = row0 + wm * 64 + m * 16 + lg * 4;        // 4 consecutive tokens
        int bb = s0 >> 11, sl = s0 & (S_LEN - 1);
        uint2 o2;
        o2.x = cvt_pk_bf16(acc[m][n][0], acc[m][n][1]);
        o2.y = cvt_pk_bf16(acc[m][n][2], acc[m][n][3]);
        *(uint2*)(Vt + ((size_t)((bb * N_KVH + kvh) * HD + d)) * S_LEN + sl) = o2;
      }
  }
}

// ---------------- pipelined NT GEMM (wo projection): 128x256 tile, triple-buffer ----------------
template <typename OutT>
__global__ __launch_bounds__(512, 2) void gemm_tpl(const unsigned short* __restrict__ A,
                                                   const unsigned short* __restrict__ Bm,
                                                   OutT* __restrict__ C,
                                                   int M, int N, int K, int nbn){
  extern __shared__ char smem[];   // 3 slots x (sA 16KB | sB 32KB) = 144KB
  int bid = blockIdx.x;
  bid = (bid & 7) * (gridDim.x >> 3) + (bid >> 3);   // XCD swizzle (nwg % 8 == 0)
  int bn = bid % nbn, bm = bid / nbn;
  int row0 = bm * 128, col0 = bn * 256;
  int t = threadIdx.x, w = t >> 6, l = t & 63;
  int lr = l & 15, lg = l >> 4;
  int wm = w >> 2, wn = w & 3;
  int srow = t >> 3;
  int sg = (t & 7) ^ (srow & 7);
  const unsigned short* agp = A + (size_t)(row0 + srow) * K + sg * 8;
  const unsigned short* bgp = Bm + (size_t)(col0 + srow) * K + sg * 8;
  int nk = K >> 6;
  f32x4 acc[4][4] = {};

#define TPL_STAGE(j, s) do {                                                   \
    char* base_ = smem + (s) * 49152;                                          \
    int k0_ = (j) << 6;                                                        \
    _Pragma("unroll")                                                          \
    for (int i_ = 0; i_ < 2; i_++)                                             \
      gload16(agp + (size_t)i_ * 64 * K + k0_, base_ + i_ * 8192 + w * 1024);  \
    _Pragma("unroll")                                                          \
    for (int i_ = 0; i_ < 4; i_++)                                             \
      gload16(bgp + (size_t)i_ * 64 * K + k0_, base_ + 16384 + i_ * 8192 + w * 1024); \
  } while(0)

  TPL_STAGE(0, 0);
  TPL_STAGE(1, 1);
  int slot = 0;
  for (int j = 0; j < nk; j++){
    if (j + 1 < nk) asm volatile("s_waitcnt vmcnt(6)" ::: "memory");
    else            asm volatile("s_waitcnt vmcnt(0)" ::: "memory");
    __builtin_amdgcn_s_barrier();
    asm volatile("" ::: "memory");
    char* sA = smem + slot * 49152;
    char* sB = sA + 16384;
    bf16x8 af[2][4], bf[2][4];
#pragma unroll
    for (int kk = 0; kk < 2; kk++){
#pragma unroll
      for (int m = 0; m < 4; m++){
        int row = wm * 64 + m * 16 + lr;
        int kg = kk * 4 + lg;
        af[kk][m] = *(const bf16x8*)(sA + row * 128 + ((kg ^ (row & 7)) << 4));
      }
#pragma unroll
      for (int n = 0; n < 4; n++){
        int row = wn * 64 + n * 16 + lr;
        int kg = kk * 4 + lg;
        bf[kk][n] = *(const bf16x8*)(sB + row * 128 + ((kg ^ (row & 7)) << 4));
      }
    }
    if (j + 2 < nk){
      int sn = slot + 2; if (sn >= 3) sn -= 3;
      TPL_STAGE(j + 2, sn);
    }
    __builtin_amdgcn_s_setprio(1);
#pragma unroll
    for (int kk = 0; kk < 2; kk++)
#pragma unroll
      for (int m = 0; m < 4; m++)
#pragma unroll
        for (int n = 0; n < 4; n++)
          acc[m][n] = __builtin_amdgcn_mfma_f32_16x16x32_bf16(af[kk][m], bf[kk][n], acc[m][n], 0, 0, 0);
    __builtin_amdgcn_s_setprio(0);
    slot++; if (slot == 3) slot = 0;
  }
#undef TPL_STAGE
#pragma unroll
  for (int m = 0; m < 4; m++)
#pragma unroll
    for (int n = 0; n < 4; n++)
#pragma unroll
      for (int r = 0; r < 4; r++){
        int rr = row0 + wm * 64 + m * 16 + lg * 4 + r;
        int cc = col0 + wn * 64 + n * 16 + lr;
        storeC(C, (size_t)rr * N + cc, acc[m][n][r]);
      }
}

// ---------------- flash attention fwd (balanced kv-split, XOR-swizzle staging) ----------------
// grid 512 = b(2) x h(16) x slot(16); slot = {pair p in 0..7, half}. QBLK=128 (4 waves x 32q).
// Per q-tile qt: kv-tiles(64) lo [0,qt+1), hi [qt+1,2qt+2) -> exactly 17 tiles per block.
__global__ __launch_bounds__(256, 2) void attn_fwd(const unsigned short* __restrict__ Q,
                                                   const unsigned short* __restrict__ Kb,
                                                   const unsigned short* __restrict__ Vt,
                                                   unsigned short* __restrict__ P0,
                                                   unsigned short* __restrict__ P1,
                                                   float2* __restrict__ ML){
  extern __shared__ char smem[];  // 2 x (sK 16KB | sV 16KB) = 64KB
  const float SOFT_C = 0.088388347648318447f * 1.4426950408889634f; // scale*log2(e)
  const float THR_RAW = 62.0f;                                      // ~8 / SOFT_C
  int bid = blockIdx.x;
  bid = ((bid & 7) << 6) | (bid >> 3);   // XCD swizzle: 64 consecutive logical per XCD
  int slot = bid & 15, h = (bid >> 4) & 15, b = bid >> 8;
  int p = slot & 7, half = slot >> 3;
  int kvh = h >> 2;
  int t = threadIdx.x, w = t >> 6, l = t & 63;
  int lq = l & 31, lh = l >> 5;
  unsigned short* Pout = half ? P1 : P0;
  float2* mlb = ML + half * (N_B * S_LEN * N_H);

  // ---- staging pointers (source pre-swizzled; LDS dest linear) ----
  int gA = (t & 15) ^ (t >> 4);
  const unsigned short* kgp = Kb + ((size_t)(b * S_LEN) + (t >> 4)) * LDK + kvh * HD + gA * 8;
  int gV = (t & 7) ^ ((t >> 3) & 7);
  const unsigned short* vgp = Vt + ((size_t)((b * N_KVH + kvh) * HD) + (t >> 3)) * S_LEN + gV * 8;

  for (int phase = 0; phase < 2; phase++){
    int qt = phase ? (15 - p) : p;
    int q_lane = qt * 128 + w * 32 + lq;
    const unsigned short* qbase = Q + ((size_t)(b * S_LEN + q_lane)) * LDQ + h * HD + lh * 8;
    bf16x8 qf[8];
#pragma unroll
    for (int ks = 0; ks < 8; ks++)
      qf[ks] = *(const bf16x8*)(qbase + ks * 16);

    f32x16 o_acc[4] = {};
    float m_run = -1e4f, l_run = 0.f;
    int t_begin = half ? (qt + 1) : 0;
    int t_end   = half ? (2 * qt + 2) : (qt + 1);

    // prologue: stage tile t_begin into buffer 0
    int pk0 = t_begin * 64;
#pragma unroll
    for (int m = 0; m < 4; m++)
      gload16(kgp + (size_t)(pk0 + m * 16) * LDK, smem + m * 4096 + w * 1024);
#pragma unroll
    for (int i = 0; i < 4; i++)
      gload16(vgp + (size_t)i * 32 * S_LEN + pk0, smem + 16384 + i * 4096 + w * 1024);
    __syncthreads();

    int cur = 0;
    for (int tix = t_begin; tix < t_end; tix++){
      int k0 = tix * 64;
      char* sK = smem + (cur << 15);
      char* sV = sK + 16384;
      if (tix + 1 < t_end){
        char* nb = smem + ((cur ^ 1) << 15);
        int nk0 = k0 + 64;
#pragma unroll
        for (int m = 0; m < 4; m++)
          gload16(kgp + (size_t)(nk0 + m * 16) * LDK, nb + m * 4096 + w * 1024);
#pragma unroll
        for (int i = 0; i < 4; i++)
          gload16(vgp + (size_t)i * 32 * S_LEN + nk0, nb + 16384 + i * 4096 + w * 1024);
      }

      // ---- QK^T (swapped): sc[n] = S^T, row=kv = n*32+(reg&3)+8*(reg>>2)+4*lh, col=q=lq ----
      f32x16 sc[2] = {};
      __builtin_amdgcn_s_setprio(1);
#pragma unroll
      for (int ks = 0; ks < 8; ks++){
#pragma unroll
        for (int n = 0; n < 2; n++){
          int row = n * 32 + lq;
          int pg = (ks * 2 + lh) ^ (row & 15);
          bf16x8 kf = *(const bf16x8*)(sK + row * 256 + pg * 16);
          sc[n] = __builtin_amdgcn_mfma_f32_32x32x16_bf16(kf, qf[ks], sc[n], 0, 0, 0);
        }
      }
      __builtin_amdgcn_s_setprio(0);
      // ---- causal mask: only the last two global tiles of this q-tile intersect the diagonal ----
      if (tix >= 2 * qt){
#pragma unroll
        for (int n = 0; n < 2; n++)
#pragma unroll
          for (int reg = 0; reg < 16; reg++){
            int kv = k0 + n * 32 + (reg & 3) + 8 * (reg >> 2) + 4 * lh;
            if (kv > q_lane) sc[n][reg] = -1e30f;
          }
      }
      // ---- online softmax (defer-max); lanes l, l^32 share q-row ----
      float tmax = sc[0][0];
#pragma unroll
      for (int n = 0; n < 2; n++)
#pragma unroll
        for (int reg = 0; reg < 16; reg++) tmax = fmaxf(tmax, sc[n][reg]);
      tmax = fmaxf(tmax, __shfl_xor(tmax, 32));
      if (!__all(tmax - m_run <= THR_RAW)){
        float nm = fmaxf(m_run, tmax);
        float rs = exp2f((m_run - nm) * SOFT_C);
        m_run = nm;
        l_run *= rs;
#pragma unroll
        for (int n = 0; n < 4; n++)
#pragma unroll
          for (int j = 0; j < 16; j++) o_acc[n][j] *= rs;
      }
      float lsum = 0.f;
#pragma unroll
      for (int n = 0; n < 2; n++)
#pragma unroll
        for (int reg = 0; reg < 16; reg++){
          float pv = exp2f((sc[n][reg] - m_run) * SOFT_C);
          sc[n][reg] = pv;
          lsum += pv;
        }
      lsum += __shfl_xor(lsum, 32);
      l_run += lsum;

      // ---- P^T -> PV B-frags: 4 cvt_pk + 2 permlane32_swap per k-step ----
      bf16x8 pb[4];
#pragma unroll
      for (int ks = 0; ks < 4; ks++){
        int n = ks >> 1;
        int R0 = (2 * ks) & 3, R1 = (2 * ks + 1) & 3;
        unsigned int WA0 = cvt_pk_bf16(sc[n][4 * R0 + 0], sc[n][4 * R0 + 1]);
        unsigned int WA1 = cvt_pk_bf16(sc[n][4 * R0 + 2], sc[n][4 * R0 + 3]);
        unsigned int WB0 = cvt_pk_bf16(sc[n][4 * R1 + 0], sc[n][4 * R1 + 1]);
        unsigned int WB1 = cvt_pk_bf16(sc[n][4 * R1 + 2], sc[n][4 * R1 + 3]);
        v2i s0 = __builtin_amdgcn_permlane32_swap((int)WA0, (int)WB0, false, false);
        v2i s1 = __builtin_amdgcn_permlane32_swap((int)WA1, (int)WB1, false, false);
        unsigned int pu[4] = {(unsigned int)s0.x, (unsigned int)s1.x,
                              (unsigned int)s0.y, (unsigned int)s1.y};
        pb[ks] = *(bf16x8*)pu;
      }
      // ---- PV: O^T += V^T * P^T ----
      __builtin_amdgcn_s_setprio(1);
#pragma unroll
      for (int n = 0; n < 4; n++){
#pragma unroll
        for (int ks = 0; ks < 4; ks++){
          int row = n * 32 + lq;
          int pg = (ks * 2 + lh) ^ (row & 7);
          bf16x8 vf = *(const bf16x8*)(sV + row * 128 + pg * 16);
          o_acc[n] = __builtin_amdgcn_mfma_f32_32x32x16_bf16(vf, pb[ks], o_acc[n], 0, 0, 0);
        }
      }
      __builtin_amdgcn_s_setprio(0);
      __syncthreads();
      cur ^= 1;
    }
    // ---- epilogue: UNNORMALIZED partial; lane holds O^T col q=lq, rows d = n*32+8g+4lh+(0..3) ----
    unsigned short* ob = Pout + ((size_t)(b * S_LEN + q_lane)) * LDQ + h * HD + 4 * lh;
#pragma unroll
    for (int n = 0; n < 4; n++)
#pragma unroll
      for (int g = 0; g < 4; g++){
        unsigned int u0 = cvt_pk_bf16(o_acc[n][4 * g + 0], o_acc[n][4 * g + 1]);
        unsigned int u1 = cvt_pk_bf16(o_acc[n][4 * g + 2], o_acc[n][4 * g + 3]);
        uint2 o2; o2.x = u0; o2.y = u1;
        *(uint2*)(ob + n * 32 + g * 8) = o2;
      }
    if (lh == 0)
      mlb[(size_t)(b * S_LEN + q_lane) * N_H + h] = make_float2(m_run, l_run);
  }
}

// ---------------- merge the two kv-half partials ----------------
__global__ void attn_merge(unsigned short* __restrict__ P0, const unsigned short* __restrict__ P1,
                           const float2* __restrict__ ML){
  const float SOFT_C = 0.088388347648318447f * 1.4426950408889634f;
  int tid = blockIdx.x * 256 + threadIdx.x;
  float2 a = ML[tid >> 4];
  float2 c = ML[(N_B * S_LEN * N_H) + (tid >> 4)];
  float m = fmaxf(a.x, c.x);
  float w0 = exp2f((a.x - m) * SOFT_C) * a.y;
  float w1 = exp2f((c.x - m) * SOFT_C) * c.y;
  float inv = 1.0f / (w0 + w1);
  float s0 = exp2f((a.x - m) * SOFT_C) * inv;
  float s1 = exp2f((c.x - m) * SOFT_C) * inv;
  uint4 u0 = *(const uint4*)(P0 + (size_t)tid * 8);
  uint4 u1 = *(const uint4*)(P1 + (size_t)tid * 8);
  unsigned short* q0 = (unsigned short*)&u0;
  unsigned short* q1 = (unsigned short*)&u1;
  uint4 o;
  unsigned int* po = (unsigned int*)&o;
#pragma unroll
  for (int j = 0; j < 4; j++){
    float lo = s0 * bf2f(q0[2*j])   + s1 * bf2f(q1[2*j]);
    float hi = s0 * bf2f(q0[2*j+1]) + s1 * bf2f(q1[2*j+1]);
    po[j] = cvt_pk_bf16(lo, hi);
  }
  *(uint4*)(P0 + (size_t)tid * 8) = o;
}

extern "C" void kernel_launch(void* const* d_in, const int* in_sizes, int n_in,
                              void* d_out, int out_size, void* d_ws, size_t ws_size,
                              hipStream_t stream) {
  const float* x  = (const float*)d_in[0];
  const float* fc = (const float*)d_in[1];
  const float* wq = (const float*)d_in[2];
  const float* wk = (const float*)d_in[3];
  const float* wv = (const float*)d_in[4];
  const float* wo = (const float*)d_in[5];
  float* out = (float*)d_out;

  char* ws = (char*)d_ws;
  unsigned short* xb  = (unsigned short*)(ws);                 // 16 MB; reused as P1 during attn
  unsigned short* wqb = (unsigned short*)(ws + 16777216);      // 8 MB; [wq|wk|wv] contiguous 12 MB
  unsigned short* wkb = (unsigned short*)(ws + 25165824);      // 2 MB
  unsigned short* wvb = (unsigned short*)(ws + 27262976);      // 2 MB
  unsigned short* wob = (unsigned short*)(ws + 29360128);      // 8 MB
  unsigned short* qb_ = (unsigned short*)(ws + 37748736);      // 16 MB  [4096,2048]
  unsigned short* kb_ = (unsigned short*)(ws + 54525952);      // 4 MB   [4096,512] roped K
  unsigned short* vtb = (unsigned short*)(ws + 62914560);      // 4 MB   [1024,2048] V^T (from gemm_qkv)
  unsigned short* ab_ = (unsigned short*)(ws + 67108864);      // 16 MB  attn partial lo / merged out
  unsigned short* p1_ = xb;                                    // 16 MB  attn partial hi
  float2*         ml_ = (float2*)wqb;                          // 1 MB   [2][4096*16] (m,l)

  // fused bf16 casts (x + 4 weights), one launch
  cast_all<<<9216, 256, 0, stream>>>(x, wq, wk, wv, wo, xb, wqb, wkb, wvb, wob);

  // fused QKV projection (B = [wq|wk|wv], N=3072): q->qb_, k->kb_, v->vtb transposed
  gemm_qkv<<<384, 512, 147456, stream>>>(xb, wqb, qb_, kb_, vtb);

  // fused RoPE: q (all 2048 cols) + k (dense [4096,512]), one launch
  rope_both<<<5120, 256, 0, stream>>>(qb_, kb_, fc);

  // attention: balanced kv-split, 512 blocks (2/CU), unnormalized partials
  attn_fwd<<<512, 256, 65536, stream>>>(qb_, kb_, vtb, ab_, p1_, ml_);
  attn_merge<<<4096, 256, 0, stream>>>(ab_, p1_, ml_);

  // output projection -> fp32 d_out via pipelined template
  gemm_tpl<float><<<256, 512, 147456, stream>>>(ab_, wob, out, 4096, 2048, 2048, 8);
}